// Round 9
// baseline (468.034 us; speedup 1.0000x reference)
//
#include <hip/hip_runtime.h>

// ---------------------------------------------------------------------------
// Self-attention (B=2,S=2048,H=2048,NH=16,HD=128), fp32 in/out, fp16 MFMA core
// Pipeline: f32->f16 convs -> QKV GEMM (8-phase-style, R8) -> flash attention
// (swapped-operand, R2) -> out GEMM (m97-style).
// R8: QKV GEMM rebuilt as 256x256/BK=32, 4-ring LDS, counted-vmcnt pipeline:
//   - ring buf r = t&3 holds K-tile t (A 16KB + B 16KB); stage for t+3 targets
//     ring (t-1)&3 whose reads finished before (lgkmcnt(0) precedes the end
//     barrier of each phase) -> provably race-free.
//   - per phase: 8 ds_read_b128 + 2 global_load_lds + barrier + lgkmcnt(0) +
//     setprio(1) + 16 MFMA + setprio(0) + counted vmcnt + barrier  (T2-T5).
// Workspace layout (bytes):
//   [0,         25165824)  w_qkv fp16  [6144][2048]
//   [25165824,  33554432)  w_o   fp16  [2048][2048]
//   [33554432,  50331648)  X fp16 [4096][2048]   (reused later as ctx fp16)
//   [50331648,  67108864)  Q fp16 [B][NH][S][HD] (pre-scaled by 1/sqrt(HD))
//   [67108864,  83886080)  K fp16 [B][NH][S][HD]
//   [83886080, 100663296)  V^T fp16 [B][NH][HD][S]   (transposed!)
// Total ws needed: 100,663,296 bytes.
// ---------------------------------------------------------------------------

typedef _Float16 half_t;
typedef _Float16 f16x8 __attribute__((ext_vector_type(8)));
typedef _Float16 f16x4 __attribute__((ext_vector_type(4)));
typedef float f32x4 __attribute__((ext_vector_type(4)));

#define AS3(p) ((__attribute__((address_space(3))) void*)(p))
#define AS1(p) ((const __attribute__((address_space(1))) void*)(p))

constexpr int B_ = 2, S_ = 2048, H_ = 2048, NH_ = 16, HD_ = 128;
constexpr int M_ = B_ * S_;      // 4096 tokens
constexpr int NQKV_ = 3 * H_;    // 6144

union U2H4 { uint2 u; f16x4 h; };
union U4H8 { uint4 u; f16x8 h; };

// ---------------------------------------------------------------------------
__global__ void f32_to_f16_kernel(const float* __restrict__ src,
                                  half_t* __restrict__ dst, int n4) {
  int i = blockIdx.x * blockDim.x + threadIdx.x;
  int stride = gridDim.x * blockDim.x;
  for (; i < n4; i += stride) {
    float4 f = reinterpret_cast<const float4*>(src)[i];
    f16x4 h;
    h[0] = (half_t)f.x; h[1] = (half_t)f.y; h[2] = (half_t)f.z; h[3] = (half_t)f.w;
    reinterpret_cast<f16x4*>(dst)[i] = h;
  }
}

// ---------------------------------------------------------------------------
// R8 QKV GEMM: C[4096][6144] = X[4096][2048] * Wqkv[6144][2048]^T + b.
// 256x256 tile, BK=32, 512 threads = 8 waves (2Mx4N), per-wave 128x64 out.
// 4-ring LDS K-tile buffers; 3-tile prefetch depth; counted vmcnt.
// LDS row = 64B (32 halves); swizzle byte ^= ((row>>1)&3)<<4 (involution,
// applied on pre-swizzled global source + on ds_read address; dest linear).
__global__ __launch_bounds__(512, 2) void gemm_qkv8(
    const half_t* __restrict__ A, const half_t* __restrict__ Bw,
    const float* __restrict__ bias,
    half_t* __restrict__ qp, half_t* __restrict__ kp, half_t* __restrict__ vp) {
  constexpr int K_ = 2048, GX = 24, NWG = 384, NT = 64;  // NT = K/32
  __shared__ __align__(16) char lds[131072];  // [ring4][A 16KB | B 16KB]
  const int tid = threadIdx.x;
  const int lane = tid & 63;
  const int wid = tid >> 6;
  const int wr = wid >> 2, wc = wid & 3;      // 2 x 4 wave grid
  const int l15 = lane & 15, lg = lane >> 4;
  const int h = blockIdx.x;
  const int orig = (h & 7) * (NWG / 8) + (h >> 3);   // XCD chunked (384%8==0)
  const int rowBase = (orig / GX) * 256;
  const int colBase = (orig % GX) * 256;

  f32x4 acc[8][4];
#pragma unroll
  for (int mf = 0; mf < 8; ++mf)
#pragma unroll
    for (int ni = 0; ni < 4; ++ni) acc[mf][ni] = {0.f, 0.f, 0.f, 0.f};

  // stage one matrix (16KB = 256 rows x 64B) of K-tile at k0 into ring
  auto stage = [&](int ring, int mat, int k0) {
#pragma unroll
    for (int pass = 0; pass < 2; ++pass) {
      int byte = pass * 8192 + tid * 16;
      int row = byte >> 6;
      int off = byte & 63;
      int qs = off ^ (((row >> 1) & 3) << 4);        // pre-swizzled source
      const half_t* g = mat
          ? (Bw + (size_t)(colBase + row) * K_ + k0 + (qs >> 1))
          : (A  + (size_t)(rowBase + row) * K_ + k0 + (qs >> 1));
      __builtin_amdgcn_global_load_lds(
          AS1(g), AS3(lds + ring * 32768 + mat * 16384 + byte), 16, 0, 0);
    }
  };

  // ---- prologue: stage tiles 0,1,2 (12 gloads/thread); gate tile 0
#pragma unroll
  for (int pt = 0; pt < 3; ++pt) { stage(pt, 0, pt * 32); stage(pt, 1, pt * 32); }
  asm volatile("s_waitcnt vmcnt(8)" ::: "memory");   // own tile-0 loads landed
  __builtin_amdgcn_s_barrier();                      // => all waves' tile 0 in

  // ---- main loop: 64 K-tiles, 2 phases each
  for (int t = 0; t < NT; ++t) {
    const int ring = t & 3;
    const int sring = (t + 3) & 3;                   // == (t-1)&3: reads done
    const int k0s = (t + 3) * 32;
    const bool dostage = (t < NT - 3);
#pragma unroll
    for (int ph = 0; ph < 2; ++ph) {
      f16x8 af[4], bf[4];
#pragma unroll
      for (int mi = 0; mi < 4; ++mi) {
        int row = wr * 128 + (ph * 4 + mi) * 16 + l15;
        af[mi] = *reinterpret_cast<const f16x8*>(
            lds + ring * 32768 + row * 64 + ((lg * 16) ^ (((row >> 1) & 3) << 4)));
      }
#pragma unroll
      for (int ni = 0; ni < 4; ++ni) {
        int row = wc * 64 + ni * 16 + l15;
        bf[ni] = *reinterpret_cast<const f16x8*>(
            lds + ring * 32768 + 16384 + row * 64 + ((lg * 16) ^ (((row >> 1) & 3) << 4)));
      }
      if (dostage) stage(sring, ph, k0s);            // ph0: A, ph1: B of t+3
      __builtin_amdgcn_s_barrier();
      asm volatile("s_waitcnt lgkmcnt(0)" ::: "memory");
      __builtin_amdgcn_sched_barrier(0);             // rule #18
      __builtin_amdgcn_s_setprio(1);
#pragma unroll
      for (int mi = 0; mi < 4; ++mi)
#pragma unroll
        for (int ni = 0; ni < 4; ++ni)
          acc[ph * 4 + mi][ni] = __builtin_amdgcn_mfma_f32_16x16x32_f16(
              af[mi], bf[ni], acc[ph * 4 + mi][ni], 0, 0, 0);
      __builtin_amdgcn_s_setprio(0);
      __builtin_amdgcn_sched_barrier(0);
      if (ph == 1) {                                 // gate next tile's reads
        if (t <= NT - 4)      asm volatile("s_waitcnt vmcnt(8)" ::: "memory");
        else if (t == NT - 3) asm volatile("s_waitcnt vmcnt(4)" ::: "memory");
        else if (t == NT - 2) asm volatile("s_waitcnt vmcnt(0)" ::: "memory");
      }
      __builtin_amdgcn_s_barrier();
    }
  }

  // ---- epilogue: scatter Q,K -> [b][h][s][d], V -> [b][h][d][s]
#pragma unroll
  for (int mf = 0; mf < 8; ++mf) {
    int trow = rowBase + wr * 128 + mf * 16 + lg * 4;
#pragma unroll
    for (int ni = 0; ni < 4; ++ni) {
      int col = colBase + wc * 64 + ni * 16 + l15;
      float bv = bias[col];
      int which = col >> 11;       // 0=q 1=k 2=v
      int rem = col & 2047;
      int head = rem >> 7;
      int d = rem & 127;
      float scl = (which == 0) ? 0.08838834764831845f : 1.0f;
#pragma unroll
      for (int r = 0; r < 4; ++r) {
        int tt = trow + r;
        int b = tt >> 11, s = tt & 2047;
        float v = (acc[mf][ni][r] + bv) * scl;
        if (which == 2) {
          vp[((size_t)((b * NH_ + head) * HD_ + d)) * S_ + s] = (half_t)v;
        } else {
          half_t* dst = (which == 0) ? qp : kp;
          dst[((size_t)((b * NH_ + head) * S_ + s)) * HD_ + d] = (half_t)v;
        }
      }
    }
  }
}

// ---------------------------------------------------------------------------
// NT GEMM (m97-style, verified): C[M][N] = A[M][K]*Bw[N][K]^T + bias, fp32 out.
// Used for the output projection only.
template <int GX, int GY>
__global__ __launch_bounds__(256, 2) void gemm_nt(
    const half_t* __restrict__ A, const half_t* __restrict__ Bw,
    const float* __restrict__ bias, float* __restrict__ outp) {
  constexpr int K_ = 2048;
  constexpr int NWG = GX * GY;
  static_assert(NWG % 8 == 0, "bijective chunked swizzle needs nwg%8==0");
  __shared__ __align__(16) half_t As[128 * 64];
  __shared__ __align__(16) half_t Bs[128 * 64];
  const int tid = threadIdx.x;
  const int lane = tid & 63;
  const int w = tid >> 6;
  const int wr = w >> 1, wc = w & 1;
  const int l15 = lane & 15, lg = lane >> 4;
  const int h = blockIdx.x;
  const int orig = (h & 7) * (NWG / 8) + (h >> 3);
  const int rowBase = (orig / GX) * 128;
  const int colBase = (orig % GX) * 128;

  f32x4 acc[4][4];
#pragma unroll
  for (int m = 0; m < 4; ++m)
#pragma unroll
    for (int n = 0; n < 4; ++n) acc[m][n] = {0.f, 0.f, 0.f, 0.f};

  for (int k0 = 0; k0 < K_; k0 += 64) {
#pragma unroll
    for (int pass = 0; pass < 4; ++pass) {
      int p = pass * 4096 + tid * 16;
      int row = p >> 7;
      int q = (p & 127) ^ ((row & 7) << 4);
      const half_t* ga = &A[(size_t)(rowBase + row) * K_ + k0 + (q >> 1)];
      __builtin_amdgcn_global_load_lds(AS1(ga), AS3((char*)As + (p & ~1023)), 16, 0, 0);
      const half_t* gb = &Bw[(size_t)(colBase + row) * K_ + k0 + (q >> 1)];
      __builtin_amdgcn_global_load_lds(AS1(gb), AS3((char*)Bs + (p & ~1023)), 16, 0, 0);
    }
    __syncthreads();
#pragma unroll
    for (int kk = 0; kk < 2; ++kk) {
      f16x8 af[4], bf[4];
#pragma unroll
      for (int m = 0; m < 4; ++m) {
        int row = wr * 64 + m * 16 + l15;
        int byte = row * 128 + ((kk * 64 + lg * 16) ^ ((row & 7) << 4));
        af[m] = *reinterpret_cast<const f16x8*>((const char*)As + byte);
      }
#pragma unroll
      for (int n = 0; n < 4; ++n) {
        int row = wc * 64 + n * 16 + l15;
        int byte = row * 128 + ((kk * 64 + lg * 16) ^ ((row & 7) << 4));
        bf[n] = *reinterpret_cast<const f16x8*>((const char*)Bs + byte);
      }
#pragma unroll
      for (int m = 0; m < 4; ++m)
#pragma unroll
        for (int n = 0; n < 4; ++n)
          acc[m][n] = __builtin_amdgcn_mfma_f32_16x16x32_f16(af[m], bf[n], acc[m][n], 0, 0, 0);
    }
    __syncthreads();
  }

#pragma unroll
  for (int m = 0; m < 4; ++m) {
    int trow = rowBase + wr * 64 + m * 16 + lg * 4;
#pragma unroll
    for (int n = 0; n < 4; ++n) {
      int col = colBase + wc * 64 + n * 16 + l15;
      float bv = bias[col];
#pragma unroll
      for (int r = 0; r < 4; ++r) {
        int t = trow + r;
        outp[(size_t)t * H_ + col] = acc[m][n][r] + bv;
      }
    }
  }
}

// ---------------------------------------------------------------------------
// Flash attention, causal (verified R8). Swapped operands; V^T staged from
// global; P relayout in-register. See R2-R7 notes.
__global__ __launch_bounds__(256, 4) void attn_kernel(
    const half_t* __restrict__ qp, const half_t* __restrict__ kp,
    const half_t* __restrict__ vtp, half_t* __restrict__ ctx) {
  __shared__ __align__(16) half_t Ks[64 * 128];   // [kv][hd]  256B rows, swizzled
  __shared__ __align__(16) half_t Vt[128 * 64];   // [d][kv]   128B rows, swizzled

  const int tid = threadIdx.x;
  const int lane = tid & 63;
  const int w = tid >> 6;
  const int l15 = lane & 15, lg = lane >> 4;
  const int bh = blockIdx.y;
  const int qtile = (gridDim.x - 1) - blockIdx.x;
  const int q0 = qtile * 64;
  const int qw = q0 + w * 16;
  const int myq = qw + l15;

  f16x8 qf[4];
  {
    const half_t* qbase = qp + ((size_t)bh * S_ + myq) * HD_;
#pragma unroll
    for (int kk = 0; kk < 4; ++kk)
      qf[kk] = *reinterpret_cast<const f16x8*>(qbase + kk * 32 + lg * 8);
  }

  f32x4 oacc[8];
#pragma unroll
  for (int d = 0; d < 8; ++d) oacc[d] = {0.f, 0.f, 0.f, 0.f};
  float mrun = -1e30f, lrun = 0.f;

  const int nt = qtile + 1;
  for (int t = 0; t < nt; ++t) {
    const int k0 = t * 64;
    __syncthreads();
#pragma unroll
    for (int pass = 0; pass < 4; ++pass) {
      int p = pass * 4096 + tid * 16;
      int row = p >> 8;
      int q = (p & 255) ^ ((row & 7) << 4);
      const half_t* g = &kp[((size_t)bh * S_ + k0 + row) * HD_ + (q >> 1)];
      __builtin_amdgcn_global_load_lds(AS1(g), AS3((char*)Ks + (p & ~1023)), 16, 0, 0);
    }
#pragma unroll
    for (int pass = 0; pass < 4; ++pass) {
      int p = pass * 4096 + tid * 16;
      int row = p >> 7;
      int q = (p & 127) ^ ((row & 7) << 4);
      const half_t* g = &vtp[((size_t)bh * HD_ + row) * S_ + k0 + (q >> 1)];
      __builtin_amdgcn_global_load_lds(AS1(g), AS3((char*)Vt + (p & ~1023)), 16, 0, 0);
    }
    __syncthreads();

    f32x4 sc[4];
#pragma unroll
    for (int c = 0; c < 4; ++c) sc[c] = {0.f, 0.f, 0.f, 0.f};
#pragma unroll
    for (int kk = 0; kk < 4; ++kk) {
#pragma unroll
      for (int c = 0; c < 4; ++c) {
        int row = c * 16 + l15;
        int byte = row * 256 + ((kk * 64 + lg * 16) ^ ((row & 7) << 4));
        f16x8 kf = *reinterpret_cast<const f16x8*>((const char*)Ks + byte);
        sc[c] = __builtin_amdgcn_mfma_f32_16x16x32_f16(kf, qf[kk], sc[c], 0, 0, 0);
      }
    }

    float tm = -1e30f;
#pragma unroll
    for (int c = 0; c < 4; ++c) {
#pragma unroll
      for (int r = 0; r < 4; ++r) {
        int kg = k0 + c * 16 + lg * 4 + r;
        float s = (kg <= myq) ? sc[c][r] : -10000.0f;
        sc[c][r] = s;
        tm = fmaxf(tm, s);
      }
    }
    tm = fmaxf(tm, __shfl_xor(tm, 16));
    tm = fmaxf(tm, __shfl_xor(tm, 32));

    float mnew = fmaxf(mrun, tm);
    float alpha = __expf(mrun - mnew);
    mrun = mnew;
    float rs = 0.f;
#pragma unroll
    for (int c = 0; c < 4; ++c)
#pragma unroll
      for (int r = 0; r < 4; ++r) {
        float pv = __expf(sc[c][r] - mrun);
        sc[c][r] = pv;
        rs += pv;
      }
    rs += __shfl_xor(rs, 16);
    rs += __shfl_xor(rs, 32);
    lrun = lrun * alpha + rs;
#pragma unroll
    for (int d = 0; d < 8; ++d) oacc[d] *= alpha;

    uint2 pp[4];
#pragma unroll
    for (int c = 0; c < 4; ++c) {
      U2H4 u;
      u.h[0] = (half_t)sc[c][0]; u.h[1] = (half_t)sc[c][1];
      u.h[2] = (half_t)sc[c][2]; u.h[3] = (half_t)sc[c][3];
      pp[c] = u.u;
    }
    const int sA = (((2 * lg) & 3) << 4) + l15;
    const int sB = (((2 * lg + 1) & 3) << 4) + l15;
    const bool hi = (lg >= 2);
    f16x8 pf[2];
#pragma unroll
    for (int kk = 0; kk < 2; ++kk) {
      uint2 e = pp[2 * kk], o = pp[2 * kk + 1];
      uint2 ae, ao, be, bo;
      ae.x = __shfl((int)e.x, sA); ae.y = __shfl((int)e.y, sA);
      ao.x = __shfl((int)o.x, sA); ao.y = __shfl((int)o.y, sA);
      be.x = __shfl((int)e.x, sB); be.y = __shfl((int)e.y, sB);
      bo.x = __shfl((int)o.x, sB); bo.y = __shfl((int)o.y, sB);
      uint2 first = hi ? ao : ae;
      uint2 second = hi ? bo : be;
      U4H8 u; u.u = make_uint4(first.x, first.y, second.x, second.y);
      pf[kk] = u.h;
    }

#pragma unroll
    for (int dc = 0; dc < 8; ++dc) {
      int row = dc * 16 + l15;
#pragma unroll
      for (int kk = 0; kk < 2; ++kk) {
        int byte = row * 128 + ((kk * 64 + lg * 16) ^ ((row & 7) << 4));
        f16x8 vf = *reinterpret_cast<const f16x8*>((const char*)Vt + byte);
        oacc[dc] = __builtin_amdgcn_mfma_f32_16x16x32_f16(vf, pf[kk], oacc[dc], 0, 0, 0);
      }
    }
  }

  const int b = bh >> 4, h = bh & 15;
  const float rl = 1.0f / lrun;
  half_t* cbase = ctx + ((size_t)(b * S_ + myq)) * H_ + h * HD_;
#pragma unroll
  for (int dc = 0; dc < 8; ++dc) {
    U2H4 u;
    u.h[0] = (half_t)(oacc[dc][0] * rl);
    u.h[1] = (half_t)(oacc[dc][1] * rl);
    u.h[2] = (half_t)(oacc[dc][2] * rl);
    u.h[3] = (half_t)(oacc[dc][3] * rl);
    *reinterpret_cast<uint2*>(cbase + dc * 16 + lg * 4) = u.u;
  }
}

// ---------------------------------------------------------------------------
extern "C" void kernel_launch(void* const* d_in, const int* in_sizes, int n_in,
                              void* d_out, int out_size, void* d_ws, size_t ws_size,
                              hipStream_t stream) {
  (void)in_sizes; (void)n_in; (void)out_size; (void)ws_size;
  const float* hidden = (const float*)d_in[0];
  // d_in[1] is the multiplicative causal mask; causality is implemented directly.
  const float* w_qkv = (const float*)d_in[2];
  const float* b_qkv = (const float*)d_in[3];
  const float* w_o   = (const float*)d_in[4];
  const float* b_o   = (const float*)d_in[5];
  float* out = (float*)d_out;

  char* ws = (char*)d_ws;
  half_t* wqkvb = (half_t*)(ws + 0);          // 25,165,824 B
  half_t* wob   = (half_t*)(ws + 25165824);   //  8,388,608 B
  half_t* xb    = (half_t*)(ws + 33554432);   // 16,777,216 B (reused as ctx)
  half_t* qws   = (half_t*)(ws + 50331648);   // 16,777,216 B
  half_t* kws   = (half_t*)(ws + 67108864);   // 16,777,216 B
  half_t* vtws  = (half_t*)(ws + 83886080);   // 16,777,216 B (V^T [b][h][d][s])
  half_t* ctx   = xb;  // safe: xb consumed by gemm_qkv8 before attn writes ctx

  f32_to_f16_kernel<<<2048, 256, 0, stream>>>(hidden, xb, M_ * H_ / 4);
  f32_to_f16_kernel<<<2048, 256, 0, stream>>>(w_qkv, wqkvb, NQKV_ * H_ / 4);
  f32_to_f16_kernel<<<2048, 256, 0, stream>>>(w_o, wob, H_ * H_ / 4);

  gemm_qkv8<<<384, 512, 0, stream>>>(xb, wqkvb, b_qkv, qws, kws, vtws);

  attn_kernel<<<dim3(S_ / 64, B_ * NH_), 256, 0, stream>>>(qws, kws, vtws, ctx);

  gemm_nt<H_ / 128, M_ / 128><<<(H_ / 128) * (M_ / 128), 256, 0, stream>>>(
      ctx, wob, b_o, out);
}